// Round 6
// baseline (1618.679 us; speedup 1.0000x reference)
//
#include <hip/hip_runtime.h>
#include <hip/hip_bf16.h>

#define D 48
#define GNUM 64
#define HDIM 128
#define ODIM 12
#define BN_EPS 1e-5f

typedef _Float16 half4v __attribute__((ext_vector_type(4)));
typedef float f32x4 __attribute__((ext_vector_type(4)));

// v_mfma_f32_16x16x16_f16: A/B = 4 x f16 per lane, C/D = 4 x f32 per lane.
#define MFMA16(a, b, c) __builtin_amdgcn_mfma_f32_16x16x16f16((a), (b), (c), 0, 0, 0)

// ---------------- setup kernels ----------------

__global__ __launch_bounds__(256) void k_deg(const int* __restrict__ row, int* __restrict__ deg, int E) {
    int e = blockIdx.x * 256 + threadIdx.x;
    if (e < E) atomicAdd(&deg[row[e]], 1);
}

// scan over deg + dinv fused.
__global__ __launch_bounds__(256) void k_scan1(const int* __restrict__ deg, int* __restrict__ incl,
                                               int* __restrict__ bsum, float* __restrict__ dinv, int N) {
    __shared__ int s[256];
    int i = blockIdx.x * 256 + threadIdx.x;
    int d = (i < N) ? deg[i] : 0;
    if (i < N) dinv[i] = d > 0 ? rsqrtf((float)d) : 0.f;
    s[threadIdx.x] = d;
    __syncthreads();
    for (int off = 1; off < 256; off <<= 1) {
        int t = (threadIdx.x >= off) ? s[threadIdx.x - off] : 0;
        __syncthreads();
        s[threadIdx.x] += t;
        __syncthreads();
    }
    if (i < N) incl[i] = s[threadIdx.x];
    if (threadIdx.x == 255) bsum[blockIdx.x] = s[255];
}

__global__ __launch_bounds__(512) void k_scan2(int* __restrict__ bsum, int nb) {
    __shared__ int s[512];
    int t = threadIdx.x;
    s[t] = (t < nb) ? bsum[t] : 0;
    __syncthreads();
    for (int off = 1; off < 512; off <<= 1) {
        int v = (t >= off) ? s[t - off] : 0;
        __syncthreads();
        s[t] += v;
        __syncthreads();
    }
    if (t < nb) bsum[t] = s[t];
}

__global__ __launch_bounds__(256) void k_scan3(const int* __restrict__ incl, const int* __restrict__ bsum,
                                               int* __restrict__ rowptr, int N) {
    int i = blockIdx.x * 256 + threadIdx.x;
    if (i < N) {
        int add = (blockIdx.x > 0) ? bsum[blockIdx.x - 1] : 0;
        rowptr[i + 1] = incl[i] + add;
    }
    if (i == 0) rowptr[0] = 0;
}

// ---------------- two-level bucketed CSR fill ----------------
// Buckets of 512 rows (b = r>>9, NB<=256 for N<=131072) x 8 XCD partition labels.
// Every write window is XCD-private and L2-resident -> no cross-XCD partial-line
// ping-pong (round 2-5 lesson: direct random 8B scatter = 8x HBM write amplification).

// Pass A: per-(bucket,part) counts. Grid/loop MUST match k_bscat exactly.
__global__ __launch_bounds__(256) void k_bcnt(const int* __restrict__ row, int* __restrict__ bcnt, int E) {
    __shared__ int h[256];
    h[threadIdx.x] = 0;
    __syncthreads();
    int part = blockIdx.x & 7;
    for (int e = blockIdx.x * 256 + threadIdx.x; e < E; e += gridDim.x * 256)
        atomicAdd(&h[row[e] >> 9], 1);
    __syncthreads();
    int c = h[threadIdx.x];
    if (c) atomicAdd(&bcnt[(threadIdx.x << 3) | part], c);
}

// Pass scan: exclusive scan of M<=2048 sub-region sizes; bfill starts at bstart.
__global__ __launch_bounds__(512) void k_bscan(const int* __restrict__ bcnt, int* __restrict__ bstart,
                                               int* __restrict__ bfill, int M) {
    __shared__ int s[512];
    int t = threadIdx.x;
    int vals[4];
    int acc = 0;
#pragma unroll
    for (int k = 0; k < 4; ++k) {
        int i = t * 4 + k;
        vals[k] = (i < M) ? bcnt[i] : 0;
        acc += vals[k];
    }
    s[t] = acc;
    __syncthreads();
    for (int off = 1; off < 512; off <<= 1) {
        int v = (t >= off) ? s[t - off] : 0;
        __syncthreads();
        s[t] += v;
        __syncthreads();
    }
    int ex = s[t] - acc;
#pragma unroll
    for (int k = 0; k < 4; ++k) {
        int i = t * 4 + k;
        if (i < M) { bstart[i] = ex; bfill[i] = ex; }
        ex += vals[k];
    }
}

// Pass B: scatter (r,c) into bucket-major ebuf. Same grid/loop/part as k_bcnt.
__global__ __launch_bounds__(256) void k_bscat(const int* __restrict__ row, const int* __restrict__ col,
                                               int* __restrict__ bfill, int2* __restrict__ ebuf, int E) {
    int part = blockIdx.x & 7;
    for (int e = blockIdx.x * 256 + threadIdx.x; e < E; e += gridDim.x * 256) {
        int r = row[e], c = col[e];
        int pos = atomicAdd(&bfill[((r >> 9) << 3) | part], 1);
        ebuf[pos] = make_int2(r, c);
    }
}

// Pass C: sequential sweep of ebuf -> final epair. XCD-chunked so consecutive
// (same-bucket) chunks stay on one XCD; epair writes land in ~65KB/bucket windows.
__global__ __launch_bounds__(256) void k_cfill(const int2* __restrict__ ebuf, const int* __restrict__ rowptr,
                                               int* __restrict__ fillc, const float* __restrict__ dinv,
                                               int2* __restrict__ epair, int E) {
    int part = blockIdx.x >> 8;   // 2048 blocks -> 8 parts x 256 blocks
    int sub = blockIdx.x & 255;
    int lo = (int)((long long)E * part / 8);
    int hi = (int)((long long)E * (part + 1) / 8);
    for (int e = lo + sub * 256 + threadIdx.x; e < hi; e += 256 * 256) {
        int2 rc = ebuf[e];
        int pos = rowptr[rc.x] + atomicAdd(&fillc[rc.x], 1);
        epair[pos] = make_int2(rc.y, __float_as_int(dinv[rc.y]));
    }
}

__global__ __launch_bounds__(256) void k_cvt(const float* __restrict__ x, _Float16* __restrict__ xh, int n4) {
    int i = blockIdx.x * 256 + threadIdx.x;
    if (i < n4) {
        float4 v = ((const float4*)x)[i];
        half4v h;
        h.x = (_Float16)v.x; h.y = (_Float16)v.y; h.z = (_Float16)v.z; h.w = (_Float16)v.w;
        ((half4v*)xh)[i] = h;
    }
}

// Precompute MFMA B-fragments of W in exact lane order, once.
__global__ __launch_bounds__(256) void k_wb(const float* __restrict__ W, _Float16* __restrict__ WB) {
    int idx = blockIdx.x * 256 + threadIdx.x;
    if (idx < 27 * 64) {
        int lane = idx & 63, ct = idx >> 6;
        int c = ct / 3, tl = ct % 3;
        int col = lane & 15, kg = lane >> 4;
        half4v h;
#pragma unroll
        for (int j = 0; j < 4; ++j) h[j] = (_Float16)W[(c * 16 + kg * 4 + j) * 48 + tl * 16 + col];
        *(half4v*)(WB + (size_t)idx * 4) = h;
    }
}

// ---------------- gather kernels (fp16, unchanged control) ----------------

__global__ __launch_bounds__(256) void k_lhat(const _Float16* __restrict__ cur, const int* __restrict__ rowptr,
                                              const int2* __restrict__ epair, const float* __restrict__ dinv,
                                              _Float16* __restrict__ tx1, int N) {
    int lane = threadIdx.x & 63;
    int i = (blockIdx.x * 256 + threadIdx.x) >> 6;
    if (i >= N) return;
    int q = lane & 15, slot = lane >> 4;
    int qc = q < 12 ? q : 11;
    int s = rowptr[i], e = rowptr[i + 1];
    float a0 = 0.f, a1 = 0.f, a2 = 0.f, a3 = 0.f;
    int p = s + slot;
    for (; p + 12 < e; p += 16) {
        int2 e0 = epair[p], e1 = epair[p + 4], e2 = epair[p + 8], e3 = epair[p + 12];
        half4v h0 = *(const half4v*)(cur + (size_t)e0.x * D + qc * 4);
        half4v h1 = *(const half4v*)(cur + (size_t)e1.x * D + qc * 4);
        half4v h2 = *(const half4v*)(cur + (size_t)e2.x * D + qc * 4);
        half4v h3 = *(const half4v*)(cur + (size_t)e3.x * D + qc * 4);
        float w0 = __int_as_float(e0.y), w1 = __int_as_float(e1.y);
        float w2 = __int_as_float(e2.y), w3 = __int_as_float(e3.y);
        a0 += w0 * (float)h0.x + w1 * (float)h1.x + w2 * (float)h2.x + w3 * (float)h3.x;
        a1 += w0 * (float)h0.y + w1 * (float)h1.y + w2 * (float)h2.y + w3 * (float)h3.y;
        a2 += w0 * (float)h0.z + w1 * (float)h1.z + w2 * (float)h2.z + w3 * (float)h3.z;
        a3 += w0 * (float)h0.w + w1 * (float)h1.w + w2 * (float)h2.w + w3 * (float)h3.w;
    }
    for (; p < e; p += 4) {
        int2 ea = epair[p];
        float wa = __int_as_float(ea.y);
        half4v ha = *(const half4v*)(cur + (size_t)ea.x * D + qc * 4);
        a0 += wa * (float)ha.x; a1 += wa * (float)ha.y; a2 += wa * (float)ha.z; a3 += wa * (float)ha.w;
    }
    a0 += __shfl_xor(a0, 16); a1 += __shfl_xor(a1, 16); a2 += __shfl_xor(a2, 16); a3 += __shfl_xor(a3, 16);
    a0 += __shfl_xor(a0, 32); a1 += __shfl_xor(a1, 32); a2 += __shfl_xor(a2, 32); a3 += __shfl_xor(a3, 32);
    if (lane < 12) {
        float sc = -dinv[i];
        half4v o;
        o.x = (_Float16)(sc * a0); o.y = (_Float16)(sc * a1);
        o.z = (_Float16)(sc * a2); o.w = (_Float16)(sc * a3);
        *(half4v*)(tx1 + (size_t)i * D + lane * 4) = o;
    }
}

__global__ __launch_bounds__(256) void k_gather2(const _Float16* __restrict__ tx0, const _Float16* __restrict__ tx1,
                                                 const int* __restrict__ rowptr, const int2* __restrict__ epair,
                                                 const float* __restrict__ dinv, _Float16* __restrict__ tx2, int N) {
    int lane = threadIdx.x & 63;
    int i = (blockIdx.x * 256 + threadIdx.x) >> 6;
    if (i >= N) return;
    int q = lane & 15, slot = lane >> 4;
    int qc = q < 12 ? q : 11;
    int s = rowptr[i], e = rowptr[i + 1];
    float a0 = 0.f, a1 = 0.f, a2 = 0.f, a3 = 0.f;
    int p = s + slot;
    for (; p + 12 < e; p += 16) {
        int2 e0 = epair[p], e1 = epair[p + 4], e2 = epair[p + 8], e3 = epair[p + 12];
        half4v h0 = *(const half4v*)(tx1 + (size_t)e0.x * D + qc * 4);
        half4v h1 = *(const half4v*)(tx1 + (size_t)e1.x * D + qc * 4);
        half4v h2 = *(const half4v*)(tx1 + (size_t)e2.x * D + qc * 4);
        half4v h3 = *(const half4v*)(tx1 + (size_t)e3.x * D + qc * 4);
        float w0 = __int_as_float(e0.y), w1 = __int_as_float(e1.y);
        float w2 = __int_as_float(e2.y), w3 = __int_as_float(e3.y);
        a0 += w0 * (float)h0.x + w1 * (float)h1.x + w2 * (float)h2.x + w3 * (float)h3.x;
        a1 += w0 * (float)h0.y + w1 * (float)h1.y + w2 * (float)h2.y + w3 * (float)h3.y;
        a2 += w0 * (float)h0.z + w1 * (float)h1.z + w2 * (float)h2.z + w3 * (float)h3.z;
        a3 += w0 * (float)h0.w + w1 * (float)h1.w + w2 * (float)h2.w + w3 * (float)h3.w;
    }
    for (; p < e; p += 4) {
        int2 ea = epair[p];
        float wa = __int_as_float(ea.y);
        half4v ha = *(const half4v*)(tx1 + (size_t)ea.x * D + qc * 4);
        a0 += wa * (float)ha.x; a1 += wa * (float)ha.y; a2 += wa * (float)ha.z; a3 += wa * (float)ha.w;
    }
    a0 += __shfl_xor(a0, 16); a1 += __shfl_xor(a1, 16); a2 += __shfl_xor(a2, 16); a3 += __shfl_xor(a3, 16);
    a0 += __shfl_xor(a0, 32); a1 += __shfl_xor(a1, 32); a2 += __shfl_xor(a2, 32); a3 += __shfl_xor(a3, 32);
    if (lane < 12) {
        float sc = -2.f * dinv[i];
        half4v h0 = *(const half4v*)(tx0 + (size_t)i * D + lane * 4);
        half4v o;
        o.x = (_Float16)(sc * a0 - (float)h0.x); o.y = (_Float16)(sc * a1 - (float)h0.y);
        o.z = (_Float16)(sc * a2 - (float)h0.z); o.w = (_Float16)(sc * a3 - (float)h0.w);
        *(half4v*)(tx2 + (size_t)i * D + lane * 4) = o;
    }
}

// ---------------- dense: t = relu([tx0|tx1|tx2] @ W + b), MFMA + fused BN stats ----------------

__global__ __launch_bounds__(256) void k_dense(const _Float16* __restrict__ tx0, const _Float16* __restrict__ tx1,
                                               const _Float16* __restrict__ tx2, const _Float16* __restrict__ WB,
                                               const float* __restrict__ b, _Float16* __restrict__ tbuf,
                                               float* __restrict__ bnst, int N) {
    __shared__ float bns[2 * D];
    int t = threadIdx.x;
    if (t < 2 * D) bns[t] = 0.f;
    __syncthreads();

    int lane = t & 63, wave = t >> 6;
    int node0 = (blockIdx.x * 4 + wave) * 16;
    if (node0 < N) {
        int col = lane & 15, kg = lane >> 4;
        int nodeA = node0 + col;
        bool inA = nodeA < N;
        const _Float16* __restrict__ Xs[3] = {tx0 + (size_t)nodeA * D, tx1 + (size_t)nodeA * D,
                                              tx2 + (size_t)nodeA * D};
        f32x4 acc0 = {}, acc1 = {}, acc2 = {};
#pragma unroll
        for (int c = 0; c < 9; ++c) {
            half4v a = {};
            if (inA) a = *(const half4v*)(Xs[c / 3] + (c % 3) * 16 + kg * 4);
            half4v b0 = *(const half4v*)(WB + ((size_t)(c * 3 + 0) * 64 + lane) * 4);
            half4v b1 = *(const half4v*)(WB + ((size_t)(c * 3 + 1) * 64 + lane) * 4);
            half4v b2 = *(const half4v*)(WB + ((size_t)(c * 3 + 2) * 64 + lane) * 4);
            acc0 = MFMA16(a, b0, acc0);
            acc1 = MFMA16(a, b1, acc1);
            acc2 = MFMA16(a, b2, acc2);
        }
        float bc0 = b[col], bc1 = b[16 + col], bc2 = b[32 + col];
        float s0 = 0.f, q0 = 0.f, s1 = 0.f, q1 = 0.f, s2 = 0.f, q2 = 0.f;
#pragma unroll
        for (int i = 0; i < 4; ++i) {
            int nd = node0 + kg * 4 + i;
            float v0 = fmaxf(acc0[i] + bc0, 0.f);
            float v1 = fmaxf(acc1[i] + bc1, 0.f);
            float v2 = fmaxf(acc2[i] + bc2, 0.f);
            if (nd < N) {
                _Float16* o = tbuf + (size_t)nd * D;
                o[col] = (_Float16)v0;
                o[16 + col] = (_Float16)v1;
                o[32 + col] = (_Float16)v2;
                s0 += v0; q0 += v0 * v0;
                s1 += v1; q1 += v1 * v1;
                s2 += v2; q2 += v2 * v2;
            }
        }
        s0 += __shfl_xor(s0, 16); s0 += __shfl_xor(s0, 32);
        q0 += __shfl_xor(q0, 16); q0 += __shfl_xor(q0, 32);
        s1 += __shfl_xor(s1, 16); s1 += __shfl_xor(s1, 32);
        q1 += __shfl_xor(q1, 16); q1 += __shfl_xor(q1, 32);
        s2 += __shfl_xor(s2, 16); s2 += __shfl_xor(s2, 32);
        q2 += __shfl_xor(q2, 16); q2 += __shfl_xor(q2, 32);
        if (lane < 16) {
            atomicAdd(&bns[col], s0);      atomicAdd(&bns[D + col], q0);
            atomicAdd(&bns[16 + col], s1); atomicAdd(&bns[D + 16 + col], q1);
            atomicAdd(&bns[32 + col], s2); atomicAdd(&bns[D + 32 + col], q2);
        }
    }
    __syncthreads();
    if (t < 2 * D) atomicAdd(&bnst[t], bns[t]);
}

// ---------------- pool (BN scale/shift computed in-block from bnstats) ----------------

__global__ __launch_bounds__(256) void k_pool(const _Float16* __restrict__ tbuf, const int* __restrict__ rowptr,
                                              const int2* __restrict__ epair, const float* __restrict__ bnst,
                                              const float* __restrict__ gamma, const float* __restrict__ beta,
                                              float Ninv, _Float16* __restrict__ outh, int N) {
    __shared__ float ssL[2 * D];
    int t = threadIdx.x;
    if (t < D) {
        float mean = bnst[t] * Ninv;
        float var = fmaxf(bnst[D + t] * Ninv - mean * mean, 0.f);
        float sc = gamma[t] * rsqrtf(var + BN_EPS);
        ssL[t] = sc;
        ssL[D + t] = beta[t] - mean * sc;
    }
    __syncthreads();
    int lane = t & 63;
    int i = (blockIdx.x * 256 + t) >> 6;
    if (i >= N) return;
    int q = lane & 15, slot = lane >> 4;
    int qc = q < 12 ? q : 11;
    int s = rowptr[i], e = rowptr[i + 1];
    float m0 = -3.4e38f, m1 = -3.4e38f, m2 = -3.4e38f, m3 = -3.4e38f;
    float n0 = 3.4e38f, n1 = 3.4e38f, n2 = 3.4e38f, n3 = 3.4e38f;
    int p = s + slot;
    for (; p + 12 < e; p += 16) {
        int c0 = epair[p].x, c1 = epair[p + 4].x, c2 = epair[p + 8].x, c3 = epair[p + 12].x;
        half4v h0 = *(const half4v*)(tbuf + (size_t)c0 * D + qc * 4);
        half4v h1 = *(const half4v*)(tbuf + (size_t)c1 * D + qc * 4);
        half4v h2 = *(const half4v*)(tbuf + (size_t)c2 * D + qc * 4);
        half4v h3 = *(const half4v*)(tbuf + (size_t)c3 * D + qc * 4);
        float x00 = (float)h0.x, x01 = (float)h0.y, x02 = (float)h0.z, x03 = (float)h0.w;
        float x10 = (float)h1.x, x11 = (float)h1.y, x12 = (float)h1.z, x13 = (float)h1.w;
        float x20 = (float)h2.x, x21 = (float)h2.y, x22 = (float)h2.z, x23 = (float)h2.w;
        float x30 = (float)h3.x, x31 = (float)h3.y, x32 = (float)h3.z, x33 = (float)h3.w;
        m0 = fmaxf(m0, fmaxf(fmaxf(x00, x10), fmaxf(x20, x30)));
        m1 = fmaxf(m1, fmaxf(fmaxf(x01, x11), fmaxf(x21, x31)));
        m2 = fmaxf(m2, fmaxf(fmaxf(x02, x12), fmaxf(x22, x32)));
        m3 = fmaxf(m3, fmaxf(fmaxf(x03, x13), fmaxf(x23, x33)));
        n0 = fminf(n0, fminf(fminf(x00, x10), fminf(x20, x30)));
        n1 = fminf(n1, fminf(fminf(x01, x11), fminf(x21, x31)));
        n2 = fminf(n2, fminf(fminf(x02, x12), fminf(x22, x32)));
        n3 = fminf(n3, fminf(fminf(x03, x13), fminf(x23, x33)));
    }
    for (; p < e; p += 4) {
        int ca = epair[p].x;
        half4v ha = *(const half4v*)(tbuf + (size_t)ca * D + qc * 4);
        float a0 = (float)ha.x, a1 = (float)ha.y, a2 = (float)ha.z, a3 = (float)ha.w;
        m0 = fmaxf(m0, a0); m1 = fmaxf(m1, a1); m2 = fmaxf(m2, a2); m3 = fmaxf(m3, a3);
        n0 = fminf(n0, a0); n1 = fminf(n1, a1); n2 = fminf(n2, a2); n3 = fminf(n3, a3);
    }
    m0 = fmaxf(m0, __shfl_xor(m0, 16)); m1 = fmaxf(m1, __shfl_xor(m1, 16));
    m2 = fmaxf(m2, __shfl_xor(m2, 16)); m3 = fmaxf(m3, __shfl_xor(m3, 16));
    m0 = fmaxf(m0, __shfl_xor(m0, 32)); m1 = fmaxf(m1, __shfl_xor(m1, 32));
    m2 = fmaxf(m2, __shfl_xor(m2, 32)); m3 = fmaxf(m3, __shfl_xor(m3, 32));
    n0 = fminf(n0, __shfl_xor(n0, 16)); n1 = fminf(n1, __shfl_xor(n1, 16));
    n2 = fminf(n2, __shfl_xor(n2, 16)); n3 = fminf(n3, __shfl_xor(n3, 16));
    n0 = fminf(n0, __shfl_xor(n0, 32)); n1 = fminf(n1, __shfl_xor(n1, 32));
    n2 = fminf(n2, __shfl_xor(n2, 32)); n3 = fminf(n3, __shfl_xor(n3, 32));
    if (lane < 12) {
        float4 sc = *(const float4*)(ssL + lane * 4);
        float4 sh = *(const float4*)(ssL + D + lane * 4);
        half4v o;
        if (s == e) {
            o.x = (_Float16)0.f; o.y = (_Float16)0.f; o.z = (_Float16)0.f; o.w = (_Float16)0.f;
        } else {
            float v0 = (sc.x >= 0.f) ? sc.x * m0 + sh.x : sc.x * n0 + sh.x;
            float v1 = (sc.y >= 0.f) ? sc.y * m1 + sh.y : sc.y * n1 + sh.y;
            float v2 = (sc.z >= 0.f) ? sc.z * m2 + sh.z : sc.z * n2 + sh.z;
            float v3 = (sc.w >= 0.f) ? sc.w * m3 + sh.w : sc.w * n3 + sh.w;
            o.x = (_Float16)v0; o.y = (_Float16)v1; o.z = (_Float16)v2; o.w = (_Float16)v3;
        }
        *(half4v*)(outh + (size_t)i * D + lane * 4) = o;
    }
}

// ---------------- final pooling + MLP ----------------

__global__ __launch_bounds__(256) void k_gpool(const _Float16* __restrict__ outh, const int* __restrict__ batch,
                                               float* __restrict__ g, int N, int chunk) {
    int lane = threadIdx.x & 63;
    int wid = (blockIdx.x * 256 + threadIdx.x) >> 6;
    int start = wid * chunk;
    if (start >= N || lane >= 12) return;
    int end = start + chunk;
    if (end > N) end = N;
    int curb = batch[start];
    float a0 = 0.f, a1 = 0.f, a2 = 0.f, a3 = 0.f;
    for (int i = start; i < end; ++i) {
        int bi = batch[i];
        if (bi != curb) {
            atomicAdd(&g[curb * D + lane * 4 + 0], a0); atomicAdd(&g[curb * D + lane * 4 + 1], a1);
            atomicAdd(&g[curb * D + lane * 4 + 2], a2); atomicAdd(&g[curb * D + lane * 4 + 3], a3);
            curb = bi; a0 = a1 = a2 = a3 = 0.f;
        }
        half4v h = *(const half4v*)(outh + (size_t)i * D + lane * 4);
        a0 += (float)h.x; a1 += (float)h.y; a2 += (float)h.z; a3 += (float)h.w;
    }
    atomicAdd(&g[curb * D + lane * 4 + 0], a0); atomicAdd(&g[curb * D + lane * 4 + 1], a1);
    atomicAdd(&g[curb * D + lane * 4 + 2], a2); atomicAdd(&g[curb * D + lane * 4 + 3], a3);
}

__global__ __launch_bounds__(256) void k_mlp(const float* __restrict__ g, const float* __restrict__ W1,
                                             const float* __restrict__ b1, const float* __restrict__ W2,
                                             const float* __restrict__ b2, float* __restrict__ out) {
    __shared__ float gL[GNUM * D];
    __shared__ float hL[GNUM * HDIM];
    __shared__ float W1L[D * HDIM];
    int t = threadIdx.x;
    for (int i = t; i < GNUM * D; i += 256) gL[i] = g[i];
    for (int i = t; i < D * HDIM; i += 256) W1L[i] = W1[i];
    __syncthreads();
    for (int i = t; i < GNUM * HDIM; i += 256) {
        int gi = i >> 7, hj = i & 127;
        float a = b1[hj];
        for (int k = 0; k < D; ++k) a += gL[gi * D + k] * W1L[k * HDIM + hj];
        hL[i] = fmaxf(a, 0.f);
    }
    __syncthreads();
    for (int i = t; i < GNUM * ODIM; i += 256) {
        int gi = i / ODIM, oj = i % ODIM;
        float a = b2[oj];
        for (int k = 0; k < HDIM; ++k) a += hL[gi * HDIM + k] * W2[k * ODIM + oj];
        out[i] = a;
    }
}

// ---------------- launch ----------------

extern "C" void kernel_launch(void* const* d_in, const int* in_sizes, int n_in,
                              void* d_out, int out_size, void* d_ws, size_t ws_size,
                              hipStream_t stream) {
    const float* x     = (const float*)d_in[0];
    const int*   ei    = (const int*)d_in[1];
    const int*   batch = (const int*)d_in[2];
    const float* W     = (const float*)d_in[4];
    const float* b     = (const float*)d_in[5];
    const float* gamma = (const float*)d_in[6];
    const float* beta  = (const float*)d_in[7];
    const float* W1    = (const float*)d_in[8];
    const float* b1    = (const float*)d_in[9];
    const float* W2    = (const float*)d_in[10];
    const float* b2    = (const float*)d_in[11];

    int N = in_sizes[0] / D;
    int E = in_sizes[1] / 2;
    const int* row = ei;
    const int* col = ei + E;

    char* w = (char*)d_ws;
    auto alloc = [&](size_t bytes) { char* p = w; w += (bytes + 255) & ~(size_t)255; return p; };
    int*       deg     = (int*)alloc((size_t)N * 4);
    float*     dinv    = (float*)alloc((size_t)N * 4);
    int*       fillc   = (int*)alloc((size_t)N * 4);
    int*       incl    = (int*)alloc((size_t)N * 4);
    int*       bsum    = (int*)alloc(4096);
    int*       rowptr  = (int*)alloc((size_t)(N + 1) * 4);
    int*       bcnt    = (int*)alloc(2048 * 4);
    int*       bstart  = (int*)alloc(2048 * 4);
    int*       bfill   = (int*)alloc(2048 * 4);
    int2*      epair   = (int2*)alloc((size_t)E * 8);
    _Float16*  xh      = (_Float16*)alloc((size_t)N * D * 2 + 64);
    _Float16*  tx1h    = (_Float16*)alloc((size_t)N * D * 2 + 64);
    _Float16*  tx2h    = (_Float16*)alloc((size_t)N * D * 2 + 64);
    _Float16*  tbufh   = (_Float16*)alloc((size_t)N * D * 2 + 64);
    _Float16*  outh    = (_Float16*)alloc((size_t)N * D * 2 + 64);
    _Float16*  WB      = (_Float16*)alloc(27 * 64 * 4 * 2);
    float*     bnstats = (float*)alloc(5 * 2 * D * 4);   // per-step slices, zeroed once
    float*     g       = (float*)alloc((size_t)GNUM * D * 4);
    // ebuf (E*8 = 12.8MB) aliases tbufh+outh (19.2MB): dead before first k_dense write.
    int2*      ebuf    = (int2*)tbufh;

    (void)hipMemsetAsync(deg, 0, (size_t)N * 4, stream);
    (void)hipMemsetAsync(fillc, 0, (size_t)N * 4, stream);
    (void)hipMemsetAsync(bcnt, 0, 2048 * 4, stream);
    (void)hipMemsetAsync(bnstats, 0, 5 * 2 * D * 4, stream);
    (void)hipMemsetAsync(g, 0, (size_t)GNUM * D * 4, stream);

    int nbE = (E + 255) / 256;
    int nbN = (N + 255) / 256;
    int NB = (N + 511) >> 9;          // 512-row buckets (<=256 for N<=131072)
    int M = NB * 8;                   // (bucket, part) sub-regions

    k_deg<<<nbE, 256, 0, stream>>>(row, deg, E);
    k_scan1<<<nbN, 256, 0, stream>>>(deg, incl, bsum, dinv, N);
    k_scan2<<<1, 512, 0, stream>>>(bsum, nbN);
    k_scan3<<<nbN, 256, 0, stream>>>(incl, bsum, rowptr, N);
    k_bcnt<<<2048, 256, 0, stream>>>(row, bcnt, E);
    k_bscan<<<1, 512, 0, stream>>>(bcnt, bstart, bfill, M);
    k_bscat<<<2048, 256, 0, stream>>>(row, col, bfill, ebuf, E);
    k_cfill<<<2048, 256, 0, stream>>>(ebuf, rowptr, fillc, dinv, epair, E);
    int n4 = N * D / 4;
    k_cvt<<<(n4 + 255) / 256, 256, 0, stream>>>(x, xh, n4);
    k_wb<<<7, 256, 0, stream>>>(W, WB);

    int nbWave = (N * 64 + 255) / 256;
    int nbDense = (((N + 15) / 16) + 3) / 4;  // 16-node tiles, 4 waves/block
    float Ninv = 1.f / (float)N;
    const _Float16* cur = xh;
    for (int step = 0; step < 5; ++step) {
        float* bnst = bnstats + step * 2 * D;
        k_lhat<<<nbWave, 256, 0, stream>>>(cur, rowptr, epair, dinv, tx1h, N);
        k_gather2<<<nbWave, 256, 0, stream>>>(cur, tx1h, rowptr, epair, dinv, tx2h, N);
        k_dense<<<nbDense, 256, 0, stream>>>(cur, tx1h, tx2h, WB, b, tbufh, bnst, N);
        k_pool<<<nbWave, 256, 0, stream>>>(tbufh, rowptr, epair, bnst, gamma, beta, Ninv, outh, N);
        cur = outh;
    }

    int chunk = 32;
    int nwaves = (N + chunk - 1) / chunk;
    int nbG = (nwaves * 64 + 255) / 256;
    k_gpool<<<nbG, 256, 0, stream>>>(outh, batch, g, N, chunk);
    k_mlp<<<1, 256, 0, stream>>>(g, W1, b1, W2, b2, (float*)d_out);
}

// Round 8
// 1271.968 us; speedup vs baseline: 1.2726x; 1.2726x over previous
//
#include <hip/hip_runtime.h>
#include <hip/hip_bf16.h>

#define D 48
#define GNUM 64
#define HDIM 128
#define ODIM 12
#define BN_EPS 1e-5f

typedef _Float16 half4v __attribute__((ext_vector_type(4)));
typedef _Float16 half8v __attribute__((ext_vector_type(8)));
typedef float f32x4 __attribute__((ext_vector_type(4)));

// v_mfma_f32_16x16x16_f16: A/B = 4 x f16 per lane, C/D = 4 x f32 per lane.
#define MFMA16(a, b, c) __builtin_amdgcn_mfma_f32_16x16x16f16((a), (b), (c), 0, 0, 0)

// ---------------- setup kernels ----------------

__global__ __launch_bounds__(256) void k_deg(const int* __restrict__ row, int* __restrict__ deg, int E) {
    int e = blockIdx.x * 256 + threadIdx.x;
    if (e < E) atomicAdd(&deg[row[e]], 1);
}

__global__ __launch_bounds__(256) void k_scan1(const int* __restrict__ deg, int* __restrict__ incl,
                                               int* __restrict__ bsum, float* __restrict__ dinv, int N) {
    __shared__ int s[256];
    int i = blockIdx.x * 256 + threadIdx.x;
    int d = (i < N) ? deg[i] : 0;
    if (i < N) dinv[i] = d > 0 ? rsqrtf((float)d) : 0.f;
    s[threadIdx.x] = d;
    __syncthreads();
    for (int off = 1; off < 256; off <<= 1) {
        int t = (threadIdx.x >= off) ? s[threadIdx.x - off] : 0;
        __syncthreads();
        s[threadIdx.x] += t;
        __syncthreads();
    }
    if (i < N) incl[i] = s[threadIdx.x];
    if (threadIdx.x == 255) bsum[blockIdx.x] = s[255];
}

__global__ __launch_bounds__(512) void k_scan2(int* __restrict__ bsum, int nb) {
    __shared__ int s[512];
    int t = threadIdx.x;
    s[t] = (t < nb) ? bsum[t] : 0;
    __syncthreads();
    for (int off = 1; off < 512; off <<= 1) {
        int v = (t >= off) ? s[t - off] : 0;
        __syncthreads();
        s[t] += v;
        __syncthreads();
    }
    if (t < nb) bsum[t] = s[t];
}

__global__ __launch_bounds__(256) void k_scan3(const int* __restrict__ incl, const int* __restrict__ bsum,
                                               int* __restrict__ rowptr, int N) {
    int i = blockIdx.x * 256 + threadIdx.x;
    if (i < N) {
        int add = (blockIdx.x > 0) ? bsum[blockIdx.x - 1] : 0;
        rowptr[i + 1] = incl[i] + add;
    }
    if (i == 0) rowptr[0] = 0;
}

// XCD-partitioned CSR fill (round-3 best). Range-chunked [e0,e1) so each dispatch
// is ~26us -> the gather kernels finally surface in the top-5 profile.
__global__ __launch_bounds__(256) void k_fill(const int* __restrict__ row, const int* __restrict__ col,
                                              const int* __restrict__ rowptr, int* __restrict__ fillc,
                                              const float* __restrict__ dinv, int2* __restrict__ epair,
                                              int e0, int e1, int N) {
    int part = blockIdx.x & 7;
    int sub = blockIdx.x >> 3;
    int nsub = (int)(gridDim.x >> 3);
    int lo = (int)(((long long)N * part) >> 3);
    int hi = (int)(((long long)N * (part + 1)) >> 3);
    for (int e = e0 + sub * 256 + threadIdx.x; e < e1; e += nsub * 256) {
        int r = row[e];
        if (r >= lo && r < hi) {
            int c = col[e];
            int p = rowptr[r] + atomicAdd(&fillc[r], 1);
            epair[p] = make_int2(c, __float_as_int(dinv[c]));
        }
    }
}

__global__ __launch_bounds__(256) void k_cvt(const float* __restrict__ x, _Float16* __restrict__ xh, int n4) {
    int i = blockIdx.x * 256 + threadIdx.x;
    if (i < n4) {
        float4 v = ((const float4*)x)[i];
        half4v h;
        h.x = (_Float16)v.x; h.y = (_Float16)v.y; h.z = (_Float16)v.z; h.w = (_Float16)v.w;
        ((half4v*)xh)[i] = h;
    }
}

// Precompute MFMA B-fragments of W in exact lane order, once.
__global__ __launch_bounds__(256) void k_wb(const float* __restrict__ W, _Float16* __restrict__ WB) {
    int idx = blockIdx.x * 256 + threadIdx.x;
    if (idx < 27 * 64) {
        int lane = idx & 63, ct = idx >> 6;
        int c = ct / 3, tl = ct % 3;
        int col = lane & 15, kg = lane >> 4;
        half4v h;
#pragma unroll
        for (int j = 0; j < 4; ++j) h[j] = (_Float16)W[(c * 16 + kg * 4 + j) * 48 + tl * 16 + col];
        *(half4v*)(WB + (size_t)idx * 4) = h;
    }
}

// ---------------- gather kernels: 8 slots x 8 lanes, dwordx4 per lane ----------------
// One wave instruction now covers 8 edges (was 4): halves memory-instruction count
// per edge. Discriminating probe: request-rate-bound -> ~2x; line-bound -> neutral.
// Lane j<6 reads bytes [j*16, j*16+16) of the 96B row; j=6,7 clamp to j=5 (merged).

#define GATHER_REDUCE8(A)                                             \
    A##0 += __shfl_xor(A##0, 8);  A##1 += __shfl_xor(A##1, 8);        \
    A##2 += __shfl_xor(A##2, 8);  A##3 += __shfl_xor(A##3, 8);        \
    A##4 += __shfl_xor(A##4, 8);  A##5 += __shfl_xor(A##5, 8);        \
    A##6 += __shfl_xor(A##6, 8);  A##7 += __shfl_xor(A##7, 8);        \
    A##0 += __shfl_xor(A##0, 16); A##1 += __shfl_xor(A##1, 16);       \
    A##2 += __shfl_xor(A##2, 16); A##3 += __shfl_xor(A##3, 16);       \
    A##4 += __shfl_xor(A##4, 16); A##5 += __shfl_xor(A##5, 16);       \
    A##6 += __shfl_xor(A##6, 16); A##7 += __shfl_xor(A##7, 16);       \
    A##0 += __shfl_xor(A##0, 32); A##1 += __shfl_xor(A##1, 32);       \
    A##2 += __shfl_xor(A##2, 32); A##3 += __shfl_xor(A##3, 32);       \
    A##4 += __shfl_xor(A##4, 32); A##5 += __shfl_xor(A##5, 32);       \
    A##6 += __shfl_xor(A##6, 32); A##7 += __shfl_xor(A##7, 32);

__global__ __launch_bounds__(256) void k_lhat(const _Float16* __restrict__ cur, const int* __restrict__ rowptr,
                                              const int2* __restrict__ epair, const float* __restrict__ dinv,
                                              _Float16* __restrict__ tx1, int N) {
    int lane = threadIdx.x & 63;
    int i = (blockIdx.x * 256 + threadIdx.x) >> 6;
    if (i >= N) return;
    int slot = lane >> 3, j = lane & 7;
    int jb = (j < 6 ? j : 5) * 8;   // half-element offset within row
    int s = rowptr[i], e = rowptr[i + 1];
    float a0 = 0.f, a1 = 0.f, a2 = 0.f, a3 = 0.f, a4 = 0.f, a5 = 0.f, a6 = 0.f, a7 = 0.f;
    int p = s + slot;
    for (; p + 8 < e; p += 16) {
        int2 ea = epair[p], eb = epair[p + 8];
        half8v ha = *(const half8v*)(cur + (size_t)ea.x * D + jb);
        half8v hb = *(const half8v*)(cur + (size_t)eb.x * D + jb);
        float wa = __int_as_float(ea.y), wb = __int_as_float(eb.y);
        a0 += wa * (float)ha[0] + wb * (float)hb[0];
        a1 += wa * (float)ha[1] + wb * (float)hb[1];
        a2 += wa * (float)ha[2] + wb * (float)hb[2];
        a3 += wa * (float)ha[3] + wb * (float)hb[3];
        a4 += wa * (float)ha[4] + wb * (float)hb[4];
        a5 += wa * (float)ha[5] + wb * (float)hb[5];
        a6 += wa * (float)ha[6] + wb * (float)hb[6];
        a7 += wa * (float)ha[7] + wb * (float)hb[7];
    }
    if (p < e) {
        int2 ea = epair[p];
        half8v ha = *(const half8v*)(cur + (size_t)ea.x * D + jb);
        float wa = __int_as_float(ea.y);
        a0 += wa * (float)ha[0]; a1 += wa * (float)ha[1]; a2 += wa * (float)ha[2]; a3 += wa * (float)ha[3];
        a4 += wa * (float)ha[4]; a5 += wa * (float)ha[5]; a6 += wa * (float)ha[6]; a7 += wa * (float)ha[7];
    }
    GATHER_REDUCE8(a)
    if (slot == 0 && j < 6) {
        float sc = -dinv[i];
        half8v o;
        o[0] = (_Float16)(sc * a0); o[1] = (_Float16)(sc * a1);
        o[2] = (_Float16)(sc * a2); o[3] = (_Float16)(sc * a3);
        o[4] = (_Float16)(sc * a4); o[5] = (_Float16)(sc * a5);
        o[6] = (_Float16)(sc * a6); o[7] = (_Float16)(sc * a7);
        *(half8v*)(tx1 + (size_t)i * D + jb) = o;
    }
}

__global__ __launch_bounds__(256) void k_gather2(const _Float16* __restrict__ tx0, const _Float16* __restrict__ tx1,
                                                 const int* __restrict__ rowptr, const int2* __restrict__ epair,
                                                 const float* __restrict__ dinv, _Float16* __restrict__ tx2, int N) {
    int lane = threadIdx.x & 63;
    int i = (blockIdx.x * 256 + threadIdx.x) >> 6;
    if (i >= N) return;
    int slot = lane >> 3, j = lane & 7;
    int jb = (j < 6 ? j : 5) * 8;
    int s = rowptr[i], e = rowptr[i + 1];
    float a0 = 0.f, a1 = 0.f, a2 = 0.f, a3 = 0.f, a4 = 0.f, a5 = 0.f, a6 = 0.f, a7 = 0.f;
    int p = s + slot;
    for (; p + 8 < e; p += 16) {
        int2 ea = epair[p], eb = epair[p + 8];
        half8v ha = *(const half8v*)(tx1 + (size_t)ea.x * D + jb);
        half8v hb = *(const half8v*)(tx1 + (size_t)eb.x * D + jb);
        float wa = __int_as_float(ea.y), wb = __int_as_float(eb.y);
        a0 += wa * (float)ha[0] + wb * (float)hb[0];
        a1 += wa * (float)ha[1] + wb * (float)hb[1];
        a2 += wa * (float)ha[2] + wb * (float)hb[2];
        a3 += wa * (float)ha[3] + wb * (float)hb[3];
        a4 += wa * (float)ha[4] + wb * (float)hb[4];
        a5 += wa * (float)ha[5] + wb * (float)hb[5];
        a6 += wa * (float)ha[6] + wb * (float)hb[6];
        a7 += wa * (float)ha[7] + wb * (float)hb[7];
    }
    if (p < e) {
        int2 ea = epair[p];
        half8v ha = *(const half8v*)(tx1 + (size_t)ea.x * D + jb);
        float wa = __int_as_float(ea.y);
        a0 += wa * (float)ha[0]; a1 += wa * (float)ha[1]; a2 += wa * (float)ha[2]; a3 += wa * (float)ha[3];
        a4 += wa * (float)ha[4]; a5 += wa * (float)ha[5]; a6 += wa * (float)ha[6]; a7 += wa * (float)ha[7];
    }
    GATHER_REDUCE8(a)
    if (slot == 0 && j < 6) {
        float sc = -2.f * dinv[i];
        half8v h0 = *(const half8v*)(tx0 + (size_t)i * D + jb);
        half8v o;
        o[0] = (_Float16)(sc * a0 - (float)h0[0]); o[1] = (_Float16)(sc * a1 - (float)h0[1]);
        o[2] = (_Float16)(sc * a2 - (float)h0[2]); o[3] = (_Float16)(sc * a3 - (float)h0[3]);
        o[4] = (_Float16)(sc * a4 - (float)h0[4]); o[5] = (_Float16)(sc * a5 - (float)h0[5]);
        o[6] = (_Float16)(sc * a6 - (float)h0[6]); o[7] = (_Float16)(sc * a7 - (float)h0[7]);
        *(half8v*)(tx2 + (size_t)i * D + jb) = o;
    }
}

// ---------------- dense: t = relu([tx0|tx1|tx2] @ W + b), MFMA + fused BN stats ----------------
// fp16 tbuf (fp8 closed: absmax 160/180 vs 81.92 -- max-pool point dominates error).

__global__ __launch_bounds__(256) void k_dense(const _Float16* __restrict__ tx0, const _Float16* __restrict__ tx1,
                                               const _Float16* __restrict__ tx2, const _Float16* __restrict__ WB,
                                               const float* __restrict__ b, _Float16* __restrict__ tbuf,
                                               float* __restrict__ bnst, int N) {
    __shared__ float bns[2 * D];
    int t = threadIdx.x;
    if (t < 2 * D) bns[t] = 0.f;
    __syncthreads();

    int lane = t & 63, wave = t >> 6;
    int node0 = (blockIdx.x * 4 + wave) * 16;
    if (node0 < N) {
        int col = lane & 15, kg = lane >> 4;
        int nodeA = node0 + col;
        bool inA = nodeA < N;
        const _Float16* __restrict__ Xs[3] = {tx0 + (size_t)nodeA * D, tx1 + (size_t)nodeA * D,
                                              tx2 + (size_t)nodeA * D};
        f32x4 acc0 = {}, acc1 = {}, acc2 = {};
#pragma unroll
        for (int c = 0; c < 9; ++c) {
            half4v a = {};
            if (inA) a = *(const half4v*)(Xs[c / 3] + (c % 3) * 16 + kg * 4);
            half4v b0 = *(const half4v*)(WB + ((size_t)(c * 3 + 0) * 64 + lane) * 4);
            half4v b1 = *(const half4v*)(WB + ((size_t)(c * 3 + 1) * 64 + lane) * 4);
            half4v b2 = *(const half4v*)(WB + ((size_t)(c * 3 + 2) * 64 + lane) * 4);
            acc0 = MFMA16(a, b0, acc0);
            acc1 = MFMA16(a, b1, acc1);
            acc2 = MFMA16(a, b2, acc2);
        }
        float bc0 = b[col], bc1 = b[16 + col], bc2 = b[32 + col];
        float s0 = 0.f, q0 = 0.f, s1 = 0.f, q1 = 0.f, s2 = 0.f, q2 = 0.f;
#pragma unroll
        for (int i = 0; i < 4; ++i) {
            int nd = node0 + kg * 4 + i;
            float v0 = fmaxf(acc0[i] + bc0, 0.f);
            float v1 = fmaxf(acc1[i] + bc1, 0.f);
            float v2 = fmaxf(acc2[i] + bc2, 0.f);
            if (nd < N) {
                _Float16* o = tbuf + (size_t)nd * D;
                o[col] = (_Float16)v0;
                o[16 + col] = (_Float16)v1;
                o[32 + col] = (_Float16)v2;
                s0 += v0; q0 += v0 * v0;
                s1 += v1; q1 += v1 * v1;
                s2 += v2; q2 += v2 * v2;
            }
        }
        s0 += __shfl_xor(s0, 16); s0 += __shfl_xor(s0, 32);
        q0 += __shfl_xor(q0, 16); q0 += __shfl_xor(q0, 32);
        s1 += __shfl_xor(s1, 16); s1 += __shfl_xor(s1, 32);
        q1 += __shfl_xor(q1, 16); q1 += __shfl_xor(q1, 32);
        s2 += __shfl_xor(s2, 16); s2 += __shfl_xor(s2, 32);
        q2 += __shfl_xor(q2, 16); q2 += __shfl_xor(q2, 32);
        if (lane < 16) {
            atomicAdd(&bns[col], s0);      atomicAdd(&bns[D + col], q0);
            atomicAdd(&bns[16 + col], s1); atomicAdd(&bns[D + 16 + col], q1);
            atomicAdd(&bns[32 + col], s2); atomicAdd(&bns[D + 32 + col], q2);
        }
    }
    __syncthreads();
    if (t < 2 * D) atomicAdd(&bnst[t], bns[t]);
}

// ---------------- pool: 8-slot x 8-lane gather, BN applied in epilogue ----------------

__global__ __launch_bounds__(256) void k_pool(const _Float16* __restrict__ tbuf, const int* __restrict__ rowptr,
                                              const int2* __restrict__ epair, const float* __restrict__ bnst,
                                              const float* __restrict__ gamma, const float* __restrict__ beta,
                                              float Ninv, _Float16* __restrict__ outh, int N) {
    __shared__ float ssL[2 * D];
    int t = threadIdx.x;
    if (t < D) {
        float mean = bnst[t] * Ninv;
        float var = fmaxf(bnst[D + t] * Ninv - mean * mean, 0.f);
        float sc = gamma[t] * rsqrtf(var + BN_EPS);
        ssL[t] = sc;
        ssL[D + t] = beta[t] - mean * sc;
    }
    __syncthreads();
    int lane = t & 63;
    int i = (blockIdx.x * 256 + t) >> 6;
    if (i >= N) return;
    int slot = lane >> 3, j = lane & 7;
    int jb = (j < 6 ? j : 5) * 8;
    int s = rowptr[i], e = rowptr[i + 1];
    float m0 = -3.4e38f, m1 = -3.4e38f, m2 = -3.4e38f, m3 = -3.4e38f;
    float m4 = -3.4e38f, m5 = -3.4e38f, m6 = -3.4e38f, m7 = -3.4e38f;
    float n0 = 3.4e38f, n1 = 3.4e38f, n2 = 3.4e38f, n3 = 3.4e38f;
    float n4 = 3.4e38f, n5 = 3.4e38f, n6 = 3.4e38f, n7 = 3.4e38f;
    int p = s + slot;
    for (; p + 8 < e; p += 16) {
        int ca = epair[p].x, cb = epair[p + 8].x;
        half8v ha = *(const half8v*)(tbuf + (size_t)ca * D + jb);
        half8v hb = *(const half8v*)(tbuf + (size_t)cb * D + jb);
        float x0 = (float)ha[0], y0 = (float)hb[0], x1 = (float)ha[1], y1 = (float)hb[1];
        float x2 = (float)ha[2], y2 = (float)hb[2], x3 = (float)ha[3], y3 = (float)hb[3];
        float x4 = (float)ha[4], y4 = (float)hb[4], x5 = (float)ha[5], y5 = (float)hb[5];
        float x6 = (float)ha[6], y6 = (float)hb[6], x7 = (float)ha[7], y7 = (float)hb[7];
        m0 = fmaxf(m0, fmaxf(x0, y0)); m1 = fmaxf(m1, fmaxf(x1, y1));
        m2 = fmaxf(m2, fmaxf(x2, y2)); m3 = fmaxf(m3, fmaxf(x3, y3));
        m4 = fmaxf(m4, fmaxf(x4, y4)); m5 = fmaxf(m5, fmaxf(x5, y5));
        m6 = fmaxf(m6, fmaxf(x6, y6)); m7 = fmaxf(m7, fmaxf(x7, y7));
        n0 = fminf(n0, fminf(x0, y0)); n1 = fminf(n1, fminf(x1, y1));
        n2 = fminf(n2, fminf(x2, y2)); n3 = fminf(n3, fminf(x3, y3));
        n4 = fminf(n4, fminf(x4, y4)); n5 = fminf(n5, fminf(x5, y5));
        n6 = fminf(n6, fminf(x6, y6)); n7 = fminf(n7, fminf(x7, y7));
    }
    if (p < e) {
        int ca = epair[p].x;
        half8v ha = *(const half8v*)(tbuf + (size_t)ca * D + jb);
        float x0 = (float)ha[0], x1 = (float)ha[1], x2 = (float)ha[2], x3 = (float)ha[3];
        float x4 = (float)ha[4], x5 = (float)ha[5], x6 = (float)ha[6], x7 = (float)ha[7];
        m0 = fmaxf(m0, x0); m1 = fmaxf(m1, x1); m2 = fmaxf(m2, x2); m3 = fmaxf(m3, x3);
        m4 = fmaxf(m4, x4); m5 = fmaxf(m5, x5); m6 = fmaxf(m6, x6); m7 = fmaxf(m7, x7);
        n0 = fminf(n0, x0); n1 = fminf(n1, x1); n2 = fminf(n2, x2); n3 = fminf(n3, x3);
        n4 = fminf(n4, x4); n5 = fminf(n5, x5); n6 = fminf(n6, x6); n7 = fminf(n7, x7);
    }
#define PRED8(A, OP)                                                  \
    A##0 = OP(A##0, __shfl_xor(A##0, 8));  A##1 = OP(A##1, __shfl_xor(A##1, 8));   \
    A##2 = OP(A##2, __shfl_xor(A##2, 8));  A##3 = OP(A##3, __shfl_xor(A##3, 8));   \
    A##4 = OP(A##4, __shfl_xor(A##4, 8));  A##5 = OP(A##5, __shfl_xor(A##5, 8));   \
    A##6 = OP(A##6, __shfl_xor(A##6, 8));  A##7 = OP(A##7, __shfl_xor(A##7, 8));   \
    A##0 = OP(A##0, __shfl_xor(A##0, 16)); A##1 = OP(A##1, __shfl_xor(A##1, 16));  \
    A##2 = OP(A##2, __shfl_xor(A##2, 16)); A##3 = OP(A##3, __shfl_xor(A##3, 16));  \
    A##4 = OP(A##4, __shfl_xor(A##4, 16)); A##5 = OP(A##5, __shfl_xor(A##5, 16));  \
    A##6 = OP(A##6, __shfl_xor(A##6, 16)); A##7 = OP(A##7, __shfl_xor(A##7, 16));  \
    A##0 = OP(A##0, __shfl_xor(A##0, 32)); A##1 = OP(A##1, __shfl_xor(A##1, 32));  \
    A##2 = OP(A##2, __shfl_xor(A##2, 32)); A##3 = OP(A##3, __shfl_xor(A##3, 32));  \
    A##4 = OP(A##4, __shfl_xor(A##4, 32)); A##5 = OP(A##5, __shfl_xor(A##5, 32));  \
    A##6 = OP(A##6, __shfl_xor(A##6, 32)); A##7 = OP(A##7, __shfl_xor(A##7, 32));
    PRED8(m, fmaxf)
    PRED8(n, fminf)
#undef PRED8
    if (slot == 0 && j < 6) {
        half8v o;
        if (s == e) {
#pragma unroll
            for (int k = 0; k < 8; ++k) o[k] = (_Float16)0.f;
        } else {
            float mm[8] = {m0, m1, m2, m3, m4, m5, m6, m7};
            float nn[8] = {n0, n1, n2, n3, n4, n5, n6, n7};
#pragma unroll
            for (int k = 0; k < 8; ++k) {
                float sc = ssL[jb + k], sh = ssL[D + jb + k];
                float v = (sc >= 0.f) ? sc * mm[k] + sh : sc * nn[k] + sh;
                o[k] = (_Float16)v;
            }
        }
        *(half8v*)(outh + (size_t)i * D + jb) = o;
    }
}

// ---------------- final pooling + MLP ----------------

__global__ __launch_bounds__(256) void k_gpool(const _Float16* __restrict__ outh, const int* __restrict__ batch,
                                               float* __restrict__ g, int N, int chunk) {
    int lane = threadIdx.x & 63;
    int wid = (blockIdx.x * 256 + threadIdx.x) >> 6;
    int start = wid * chunk;
    if (start >= N || lane >= 12) return;
    int end = start + chunk;
    if (end > N) end = N;
    int curb = batch[start];
    float a0 = 0.f, a1 = 0.f, a2 = 0.f, a3 = 0.f;
    for (int i = start; i < end; ++i) {
        int bi = batch[i];
        if (bi != curb) {
            atomicAdd(&g[curb * D + lane * 4 + 0], a0); atomicAdd(&g[curb * D + lane * 4 + 1], a1);
            atomicAdd(&g[curb * D + lane * 4 + 2], a2); atomicAdd(&g[curb * D + lane * 4 + 3], a3);
            curb = bi; a0 = a1 = a2 = a3 = 0.f;
        }
        half4v h = *(const half4v*)(outh + (size_t)i * D + lane * 4);
        a0 += (float)h.x; a1 += (float)h.y; a2 += (float)h.z; a3 += (float)h.w;
    }
    atomicAdd(&g[curb * D + lane * 4 + 0], a0); atomicAdd(&g[curb * D + lane * 4 + 1], a1);
    atomicAdd(&g[curb * D + lane * 4 + 2], a2); atomicAdd(&g[curb * D + lane * 4 + 3], a3);
}

__global__ __launch_bounds__(256) void k_mlp(const float* __restrict__ g, const float* __restrict__ W1,
                                             const float* __restrict__ b1, const float* __restrict__ W2,
                                             const float* __restrict__ b2, float* __restrict__ out) {
    __shared__ float gL[GNUM * D];
    __shared__ float hL[GNUM * HDIM];
    __shared__ float W1L[D * HDIM];
    int t = threadIdx.x;
    for (int i = t; i < GNUM * D; i += 256) gL[i] = g[i];
    for (int i = t; i < D * HDIM; i += 256) W1L[i] = W1[i];
    __syncthreads();
    for (int i = t; i < GNUM * HDIM; i += 256) {
        int gi = i >> 7, hj = i & 127;
        float a = b1[hj];
        for (int k = 0; k < D; ++k) a += gL[gi * D + k] * W1L[k * HDIM + hj];
        hL[i] = fmaxf(a, 0.f);
    }
    __syncthreads();
    for (int i = t; i < GNUM * ODIM; i += 256) {
        int gi = i / ODIM, oj = i % ODIM;
        float a = b2[oj];
        for (int k = 0; k < HDIM; ++k) a += hL[gi * HDIM + k] * W2[k * ODIM + oj];
        out[i] = a;
    }
}

// ---------------- launch ----------------

extern "C" void kernel_launch(void* const* d_in, const int* in_sizes, int n_in,
                              void* d_out, int out_size, void* d_ws, size_t ws_size,
                              hipStream_t stream) {
    const float* x     = (const float*)d_in[0];
    const int*   ei    = (const int*)d_in[1];
    const int*   batch = (const int*)d_in[2];
    const float* W     = (const float*)d_in[4];
    const float* b     = (const float*)d_in[5];
    const float* gamma = (const float*)d_in[6];
    const float* beta  = (const float*)d_in[7];
    const float* W1    = (const float*)d_in[8];
    const float* b1    = (const float*)d_in[9];
    const float* W2    = (const float*)d_in[10];
    const float* b2    = (const float*)d_in[11];

    int N = in_sizes[0] / D;
    int E = in_sizes[1] / 2;
    const int* row = ei;
    const int* col = ei + E;

    char* w = (char*)d_ws;
    auto alloc = [&](size_t bytes) { char* p = w; w += (bytes + 255) & ~(size_t)255; return p; };
    int*       deg     = (int*)alloc((size_t)N * 4);
    float*     dinv    = (float*)alloc((size_t)N * 4);
    int*       fillc   = (int*)alloc((size_t)N * 4);
    int*       incl    = (int*)alloc((size_t)N * 4);
    int*       bsum    = (int*)alloc(4096);
    int*       rowptr  = (int*)alloc((size_t)(N + 1) * 4);
    int2*      epair   = (int2*)alloc((size_t)E * 8);
    _Float16*  xh      = (_Float16*)alloc((size_t)N * D * 2 + 64);
    _Float16*  tx1h    = (_Float16*)alloc((size_t)N * D * 2 + 64);
    _Float16*  tx2h    = (_Float16*)alloc((size_t)N * D * 2 + 64);
    _Float16*  tbufh   = (_Float16*)alloc((size_t)N * D * 2 + 64);
    _Float16*  outh    = (_Float16*)alloc((size_t)N * D * 2 + 64);
    _Float16*  WB      = (_Float16*)alloc(27 * 64 * 4 * 2);
    float*     bnstats = (float*)alloc(5 * 2 * D * 4);   // per-step slices, zeroed once
    float*     g       = (float*)alloc((size_t)GNUM * D * 4);

    (void)hipMemsetAsync(deg, 0, (size_t)N * 4, stream);
    (void)hipMemsetAsync(fillc, 0, (size_t)N * 4, stream);
    (void)hipMemsetAsync(bnstats, 0, 5 * 2 * D * 4, stream);
    (void)hipMemsetAsync(g, 0, (size_t)GNUM * D * 4, stream);

    int nbE = (E + 255) / 256;
    int nbN = (N + 255) / 256;

    k_deg<<<nbE, 256, 0, stream>>>(row, deg, E);
    k_scan1<<<nbN, 256, 0, stream>>>(deg, incl, bsum, dinv, N);
    k_scan2<<<1, 512, 0, stream>>>(bsum, nbN);
    k_scan3<<<nbN, 256, 0, stream>>>(incl, bsum, rowptr, N);
    int E3 = E / 3;
    k_fill<<<2048, 256, 0, stream>>>(row, col, rowptr, fillc, dinv, epair, 0, E3, N);
    k_fill<<<2048, 256, 0, stream>>>(row, col, rowptr, fillc, dinv, epair, E3, 2 * E3, N);
    k_fill<<<2048, 256, 0, stream>>>(row, col, rowptr, fillc, dinv, epair, 2 * E3, E, N);
    int n4 = N * D / 4;
    k_cvt<<<(n4 + 255) / 256, 256, 0, stream>>>(x, xh, n4);
    k_wb<<<7, 256, 0, stream>>>(W, WB);

    int nbWave = (N * 64 + 255) / 256;
    int nbDense = (((N + 15) / 16) + 3) / 4;  // 16-node tiles, 4 waves/block
    float Ninv = 1.f / (float)N;
    const _Float16* cur = xh;
    for (int step = 0; step < 5; ++step) {
        float* bnst = bnstats + step * 2 * D;
        k_lhat<<<nbWave, 256, 0, stream>>>(cur, rowptr, epair, dinv, tx1h, N);
        k_gather2<<<nbWave, 256, 0, stream>>>(cur, tx1h, rowptr, epair, dinv, tx2h, N);
        k_dense<<<nbDense, 256, 0, stream>>>(cur, tx1h, tx2h, WB, b, tbufh, bnst, N);
        k_pool<<<nbWave, 256, 0, stream>>>(tbufh, rowptr, epair, bnst, gamma, beta, Ninv, outh, N);
        cur = outh;
    }

    int chunk = 32;
    int nwaves = (N + chunk - 1) / chunk;
    int nbG = (nwaves * 64 + 255) / 256;
    k_gpool<<<nbG, 256, 0, stream>>>(outh, batch, g, N, chunk);
    k_mlp<<<1, 256, 0, stream>>>(g, W1, b1, W2, b2, (float*)d_out);
}